// Round 12
// baseline (762.673 us; speedup 1.0000x reference)
//
#include <hip/hip_runtime.h>
#include <math.h>

typedef __bf16 bf16x8 __attribute__((ext_vector_type(8)));
typedef __bf16 bf16x4 __attribute__((ext_vector_type(4)));
typedef float f32x4 __attribute__((ext_vector_type(4)));
typedef unsigned short u16x8 __attribute__((ext_vector_type(8)));

#define GLD16(src, dst)                                                        \
    __builtin_amdgcn_global_load_lds(                                          \
        (const __attribute__((address_space(1))) void*)(src),                  \
        (__attribute__((address_space(3))) void*)(dst), 16, 0, 0)

__device__ inline float bf2f(unsigned short u) {
    union { unsigned int i; float f; } c;
    c.i = ((unsigned int)u) << 16;
    return c.f;
}

// ---------------- CSR build ----------------

__global__ __launch_bounds__(256) void count_kernel(const int* __restrict__ ei,
                                                    int* __restrict__ cnt, int N, int E) {
    int idx = blockIdx.x * 256 + threadIdx.x;
    if (idx >= 5 * E) return;
    int r = idx / E;
    int e = idx - r * E;
    int dst = ei[(size_t)r * 2 * E + E + e];
    atomicAdd(&cnt[r * N + dst], 1);
}

__global__ __launch_bounds__(256) void scanA_kernel(const int* __restrict__ cnt,
                                                    int* __restrict__ off,
                                                    int* __restrict__ csums, int N, int NC) {
    int r = blockIdx.y, c = blockIdx.x, t = threadIdx.x;
    int idx0 = c * 1024 + t * 4;
    int v0 = (idx0 + 0 < N) ? cnt[r * N + idx0 + 0] : 0;
    int v1 = (idx0 + 1 < N) ? cnt[r * N + idx0 + 1] : 0;
    int v2 = (idx0 + 2 < N) ? cnt[r * N + idx0 + 2] : 0;
    int v3 = (idx0 + 3 < N) ? cnt[r * N + idx0 + 3] : 0;
    int ts = v0 + v1 + v2 + v3;
    __shared__ int sd[256];
    sd[t] = ts;
    __syncthreads();
    for (int s = 1; s < 256; s <<= 1) {
        int add = (t >= s) ? sd[t - s] : 0;
        __syncthreads();
        sd[t] += add;
        __syncthreads();
    }
    int excl = sd[t] - ts;
    size_t base = (size_t)r * (N + 1);
    if (idx0 + 0 < N) off[base + idx0 + 0] = excl;
    if (idx0 + 1 < N) off[base + idx0 + 1] = excl + v0;
    if (idx0 + 2 < N) off[base + idx0 + 2] = excl + v0 + v1;
    if (idx0 + 3 < N) off[base + idx0 + 3] = excl + v0 + v1 + v2;
    if (t == 255) csums[r * NC + c] = sd[255];
}

__global__ __launch_bounds__(64) void scanB_kernel(int* __restrict__ csums,
                                                   int* __restrict__ off, int N, int NC) {
    int r = threadIdx.x;
    if (r < 5) {
        int run = 0;
        for (int c = 0; c < NC; c++) {
            int t = csums[r * NC + c];
            csums[r * NC + c] = run;
            run += t;
        }
        off[(size_t)r * (N + 1) + N] = run;
    }
}

__global__ __launch_bounds__(256) void scanC_kernel(int* __restrict__ off,
                                                    const int* __restrict__ csums,
                                                    int* __restrict__ cur,
                                                    int N, int NC) {
    int r = blockIdx.y, c = blockIdx.x, t = threadIdx.x;
    int add = csums[r * NC + c];
    int idx0 = c * 1024 + t * 4;
    size_t base = (size_t)r * (N + 1);
#pragma unroll
    for (int j = 0; j < 4; j++)
        if (idx0 + j < N) {
            int v = off[base + idx0 + j] + add;
            off[base + idx0 + j] = v;
            cur[r * N + idx0 + j] = v;
        }
}

__global__ __launch_bounds__(256) void scatter_kernel(const int* __restrict__ ei,
                                                      int* __restrict__ cur,
                                                      unsigned short* __restrict__ srcs,
                                                      int N, int E) {
    int idx = blockIdx.x * 256 + threadIdx.x;
    if (idx >= 5 * E) return;
    int r = idx / E;
    int e = idx - r * E;
    int src = ei[(size_t)r * 2 * E + e];
    int dst = ei[(size_t)r * 2 * E + E + e];
    int pos = atomicAdd(&cur[r * N + dst], 1);
    srcs[(size_t)r * E + pos] = (unsigned short)src;
}

// ---------------- x -> bf16 copy (for pearl gather) ----------------

__global__ __launch_bounds__(256) void xcvt_kernel(const float* __restrict__ x,
                                                   unsigned short* __restrict__ xb, int total) {
    int idx = (blockIdx.x * 256 + threadIdx.x) * 4;
    if (idx >= total) return;
    float4 v = *(const float4*)(x + idx);
    __bf16 b0 = (__bf16)v.x, b1 = (__bf16)v.y, b2 = (__bf16)v.z, b3 = (__bf16)v.w;
    unsigned short* p = xb + idx;
    p[0] = *(unsigned short*)&b0;
    p[1] = *(unsigned short*)&b1;
    p[2] = *(unsigned short*)&b2;
    p[3] = *(unsigned short*)&b3;
}

// ---------------- PEARL PE + time PE + concat -> h0 [N,112] ----------------
// lane = (parity p, channel-pair c): one u32 load = 2 bf16 channels of row
// k+2j+p -> one wave instruction covers 2 rows (256 B); parity-merge at end.

__global__ __launch_bounds__(256) void pearl_h0_kernel(
    const float* __restrict__ x, const unsigned short* __restrict__ xb,
    const int* __restrict__ date,
    const int* __restrict__ off, const unsigned short* __restrict__ srcs,
    const float* __restrict__ pW, const float* __restrict__ pb,
    float* __restrict__ h0, int N, int E) {
    int lane = threadIdx.x & 63;
    int wid = blockIdx.x * 4 + (threadIdx.x >> 6);
    if (wid >= N) return;
    int n = __builtin_amdgcn_readfirstlane(wid);
    int pr = lane >> 5;        // row parity
    int c2 = (lane & 31) * 2;  // channel base

    float a0 = 0.f, a1 = 0.f;
    int deg = 0;
    for (int r = 0; r < 5; r++) {
        int kb = off[(size_t)r * (N + 1) + n];
        int ke = off[(size_t)r * (N + 1) + n + 1];
        deg += ke - kb;
        const unsigned short* sp = srcs + (size_t)r * E;
        int k = kb;
        for (; k + 16 <= ke; k += 16) {
            unsigned int u[8];
#pragma unroll
            for (int j = 0; j < 8; j++) {
                int row = sp[k + 2 * j + pr];
                u[j] = *(const unsigned int*)(xb + (size_t)row * 64 + c2);
            }
#pragma unroll
            for (int j = 0; j < 8; j++) {
                a0 += bf2f((unsigned short)(u[j] & 0xffff));
                a1 += bf2f((unsigned short)(u[j] >> 16));
            }
        }
        for (; k + 2 <= ke; k += 2) {
            int row = sp[k + pr];
            unsigned int u = *(const unsigned int*)(xb + (size_t)row * 64 + c2);
            a0 += bf2f((unsigned short)(u & 0xffff));
            a1 += bf2f((unsigned short)(u >> 16));
        }
        if (k < ke) {  // odd tail: only parity-0 half contributes
            int row = sp[k];
            unsigned int u = *(const unsigned int*)(xb + (size_t)row * 64 + c2);
            if (pr == 0) {
                a0 += bf2f((unsigned short)(u & 0xffff));
                a1 += bf2f((unsigned short)(u >> 16));
            }
        }
    }
    a0 += __shfl_xor(a0, 32, 64);
    a1 += __shfl_xor(a1, 32, 64);
    float dn = fmaxf((float)deg, 1.0f);
    float an0 = a0 / dn, an1 = a1 / dn;

    float s = (lane < 32) ? pb[lane] : 0.f;
#pragma unroll
    for (int cc = 0; cc < 64; cc++) {
        float av = __shfl((cc & 1) ? an1 : an0, cc >> 1, 64);
        if (lane < 32) s = fmaf(av, pW[cc * 32 + lane], s);
    }

    h0[(size_t)n * 112 + lane] = x[(size_t)n * 64 + lane];
    if (lane < 32) h0[(size_t)n * 112 + 64 + lane] = tanhf(s);
    if (lane < 16) {
        float t = (float)date[n] / 10000.0f;
        int i = lane & 7;
        float dv = expf((float)(2 * i) * (-0.57564627324851148f));
        float arg = t * dv;
        h0[(size_t)n * 112 + 96 + lane] = (lane < 8) ? sinf(arg) : cosf(arg);
    }
}

// ---------------- pack A [M,K] fp32 -> hi/lo bf16, MFMA-fragment-major ----------------

__global__ __launch_bounds__(256) void pack_a_kernel(
    const float* __restrict__ A, __bf16* __restrict__ Ah, __bf16* __restrict__ Al,
    int M, int K, int Mp, int KT) {
    int KG = KT * 4;
    int idx = blockIdx.x * 256 + threadIdx.x;
    if (idx >= Mp * KG) return;
    int m = idx / KG, kgg = idx - m * KG;
    int kt = kgg >> 2, kg = kgg & 3;
    int k0 = kt * 32 + kg * 8;
    int mt = m >> 4, mr = m & 15;
    size_t out = (((size_t)mt * KT + kt) * 64 + kg * 16 + mr) * 8;
    bf16x8 hv, lv;
#pragma unroll
    for (int j = 0; j < 8; j++) {
        int k = k0 + j;
        float v = (m < M && k < K) ? A[(size_t)m * K + k] : 0.f;
        __bf16 h = (__bf16)v;
        hv[j] = h;
        lv[j] = (__bf16)(v - (float)h);
    }
    *(bf16x8*)(Ah + out) = hv;
    *(bf16x8*)(Al + out) = lv;
}

// ---------------- pack all weights (21 tensors, grid.y selects) ----------------

__global__ __launch_bounds__(256) void pack_w_kernel(
    const float* __restrict__ Wl0, const float* __restrict__ Wr0,
    const float* __restrict__ Wl1, const float* __restrict__ Wr1,
    const float* __restrict__ W1,
    __bf16* __restrict__ Wph, __bf16* __restrict__ Wpl) {
    const int S0 = 32768, S1 = 65536;
    int t = blockIdx.y;
    const float* W;
    int K, Nc, KT;
    size_t dst;
    if (t < 5)       { W = Wl0 + (size_t)t * 112 * 256;        K = 112; Nc = 256; KT = 4; dst = (size_t)t * S0; }
    else if (t < 10) { W = Wr0 + (size_t)(t - 5) * 112 * 256;  K = 112; Nc = 256; KT = 4; dst = 163840 + (size_t)(t - 5) * S0; }
    else if (t < 15) { W = Wl1 + (size_t)(t - 10) * 256 * 256; K = 256; Nc = 256; KT = 8; dst = 327680 + (size_t)(t - 10) * S1; }
    else if (t < 20) { W = Wr1 + (size_t)(t - 15) * 256 * 256; K = 256; Nc = 256; KT = 8; dst = 655360 + (size_t)(t - 15) * S1; }
    else             { W = W1;                                  K = 256; Nc = 128; KT = 8; dst = 983040; }
    int entries = (Nc / 16) * KT * 64;
    int idx = blockIdx.x * 256 + threadIdx.x;
    if (idx >= entries) return;
    int nt = idx / (KT * 64);
    int rem = idx - nt * (KT * 64);
    int kt = rem >> 6, lane = rem & 63;
    int kg = lane >> 4, nr = lane & 15;
    bf16x8 hv, lv;
#pragma unroll
    for (int j = 0; j < 8; j++) {
        int k = kt * 32 + kg * 8 + j;
        float v = (k < K) ? W[(size_t)k * Nc + nt * 16 + nr] : 0.f;
        __bf16 h = (__bf16)v;
        hv[j] = h;
        lv[j] = (__bf16)(v - (float)h);
    }
    *(bf16x8*)(Wph + dst + (size_t)idx * 8) = hv;
    *(bf16x8*)(Wpl + dst + (size_t)idx * 8) = lv;
}

// ---------------- split-bf16 MFMA GEMM, XCD-aware panel swizzle ----------------
// grid = ceil(MT/8)*8*NPANEL. p = g*(8*NPANEL) + panel*8 + slot: all NPANEL
// panels of one bx land on the same XCD (same p%8) -> A-tile fetched once/XCD.

__global__ __launch_bounds__(256) void gemm_mfma(
    const __bf16* __restrict__ Ah, const __bf16* __restrict__ Al,
    const __bf16* __restrict__ WLh, const __bf16* __restrict__ WLl,
    const __bf16* __restrict__ WRh, const __bf16* __restrict__ WRl,
    size_t strideB, void* __restrict__ Cl, void* __restrict__ Cr, size_t CstrideBytes,
    int M, int Nout, int KT, const float* __restrict__ bias, int do_relu,
    int npL, int npR, int out_bf16, int NYT, int MTp, int NPANEL) {
    int p = blockIdx.x;
    int stride = 8 * NPANEL;
    int g = p / stride, rem = p % stride;
    int slot = rem % 8, panel = rem / 8;
    int bx = g * 8 + slot;
    if (bx >= MTp) return;
    int by = panel % NYT;
    int side = (panel / NYT) & 1;
    int r = panel / (NYT * 2);

    const __bf16* Bh = (side ? WRh : WLh) + (size_t)r * strideB;
    const __bf16* Bl = (side ? WRl : WLl) + (size_t)r * strideB;
    char* C = (char*)(side ? Cr : Cl) + (size_t)r * CstrideBytes;
    int np = side ? npR : npL;

    __shared__ __bf16 sAh[8 * 512], sAl[8 * 512], sBh[8 * 512], sBl[8 * 512];

    int tid = threadIdx.x, lane = tid & 63, w = tid >> 6;
    int wr = w >> 1, wc = w & 1;

    f32x4 acc[4][4] = {};

    for (int kt = 0; kt < KT; ++kt) {
        int tl = w * 2;
        size_t a0 = ((size_t)(bx * 8 + tl) * KT + kt) * 512 + lane * 8;
        size_t a1 = ((size_t)(bx * 8 + tl + 1) * KT + kt) * 512 + lane * 8;
        size_t b0 = ((size_t)(by * 8 + tl) * KT + kt) * 512 + lane * 8;
        size_t b1 = ((size_t)(by * 8 + tl + 1) * KT + kt) * 512 + lane * 8;
        GLD16(Ah + a0, sAh + tl * 512);
        GLD16(Ah + a1, sAh + (tl + 1) * 512);
        GLD16(Bh + b0, sBh + tl * 512);
        GLD16(Bh + b1, sBh + (tl + 1) * 512);
        if (np >= 2) {
            GLD16(Al + a0, sAl + tl * 512);
            GLD16(Al + a1, sAl + (tl + 1) * 512);
        }
        if (np == 3) {
            GLD16(Bl + b0, sBl + tl * 512);
            GLD16(Bl + b1, sBl + (tl + 1) * 512);
        }
        __syncthreads();

        bf16x8 ah[4], al[4], bh[4], bl[4];
#pragma unroll
        for (int i = 0; i < 4; i++) {
            ah[i] = *(const bf16x8*)(sAh + (wr * 4 + i) * 512 + lane * 8);
            bh[i] = *(const bf16x8*)(sBh + (wc * 4 + i) * 512 + lane * 8);
        }
        if (np >= 2) {
#pragma unroll
            for (int i = 0; i < 4; i++)
                al[i] = *(const bf16x8*)(sAl + (wr * 4 + i) * 512 + lane * 8);
        }
        if (np == 3) {
#pragma unroll
            for (int i = 0; i < 4; i++)
                bl[i] = *(const bf16x8*)(sBl + (wc * 4 + i) * 512 + lane * 8);
        }
#pragma unroll
        for (int i = 0; i < 4; i++)
#pragma unroll
            for (int j = 0; j < 4; j++) {
                acc[i][j] = __builtin_amdgcn_mfma_f32_16x16x32_bf16(ah[i], bh[j], acc[i][j], 0, 0, 0);
                if (np >= 2)
                    acc[i][j] = __builtin_amdgcn_mfma_f32_16x16x32_bf16(al[i], bh[j], acc[i][j], 0, 0, 0);
                if (np == 3)
                    acc[i][j] = __builtin_amdgcn_mfma_f32_16x16x32_bf16(ah[i], bl[j], acc[i][j], 0, 0, 0);
            }
        __syncthreads();
    }

    int rb = bx * 128 + wr * 64, cb = by * 128 + wc * 64;
#pragma unroll
    for (int i = 0; i < 4; i++) {
#pragma unroll
        for (int j = 0; j < 4; j++) {
            int row0 = rb + i * 16 + (lane >> 4) * 4;
            int col = cb + j * 16 + (lane & 15);
            float bv = bias ? bias[col] : 0.f;
#pragma unroll
            for (int q = 0; q < 4; q++) {
                int row = row0 + q;
                if (row < M) {
                    float v = acc[i][j][q] + bv;
                    if (do_relu) v = fmaxf(v, 0.f);
                    if (out_bf16)
                        ((__bf16*)C)[(size_t)row * Nout + col] = (__bf16)v;
                    else
                        ((float*)C)[(size_t)row * Nout + col] = v;
                }
            }
        }
    }
}

// ---------------- fused GATv2 over ALL 5 relations (r7 body, 8 waves/block) ----------------

__global__ __launch_bounds__(512) void gat5_kernel(
    const unsigned short* __restrict__ xl5, const unsigned short* __restrict__ xr5,
    const float* __restrict__ att,        // [5][256]
    const int* __restrict__ csrOff,       // [5][N+1]
    const unsigned short* __restrict__ csrSrc,  // [5][E]
    __bf16* __restrict__ Ah, __bf16* __restrict__ Al,  // packed output (KT=8)
    const float* __restrict__ bvec,       // [5][256]
    int N, int E) {
    int lane = threadIdx.x & 63;
    int wid = blockIdx.x * 8 + (threadIdx.x >> 6);
    if (wid >= N) return;
    int n = __builtin_amdgcn_readfirstlane(wid);
    int e = lane >> 4;
    int sub = lane & 15;
    int cb = (sub >> 2) * 64 + (sub & 3) * 16;  // head*64 + q*16
    int wc = cb + e * 4;

    float4 cv = {0.f, 0.f, 0.f, 0.f};
#pragma unroll
    for (int r = 0; r < 5; r++) {
        float4 b = *(const float4*)(bvec + r * 256 + wc);
        cv.x += b.x; cv.y += b.y; cv.z += b.z; cv.w += b.w;
    }

    for (int r = 0; r < 5; r++) {
        const unsigned short* xl = xl5 + (size_t)r * N * 256;
        float rv[16], av[16];
        {
            const unsigned short* xrp = xr5 + ((size_t)r * N + n) * 256 + cb;
            u16x8 q0 = *(const u16x8*)(xrp);
            u16x8 q1 = *(const u16x8*)(xrp + 8);
#pragma unroll
            for (int j = 0; j < 8; j++) { rv[j] = bf2f(q0[j]); rv[8 + j] = bf2f(q1[j]); }
#pragma unroll
            for (int j = 0; j < 16; j += 4) {
                float4 a = *(const float4*)(att + r * 256 + cb + j);
                av[j] = a.x; av[j + 1] = a.y; av[j + 2] = a.z; av[j + 3] = a.w;
            }
        }

        float m = -3.0e38f, d = 0.f;
        float A[16];
#pragma unroll
        for (int j = 0; j < 16; j++) A[j] = 0.f;

        const int* off = csrOff + (size_t)r * (N + 1);
        const unsigned short* sp = csrSrc + (size_t)r * E;
        int kb = off[n], ke = off[n + 1];
        if (kb < ke) {
            int kl = ke - 1;
            int ki = kb + e;
            int s = sp[(ki <= kl) ? ki : kl];
            float c[16];
            {
                const unsigned short* xp = xl + (size_t)s * 256 + cb;
                u16x8 q0 = *(const u16x8*)(xp);
                u16x8 q1 = *(const u16x8*)(xp + 8);
#pragma unroll
                for (int j = 0; j < 8; j++) { c[j] = bf2f(q0[j]); c[8 + j] = bf2f(q1[j]); }
            }
            for (int k = kb; k < ke; k += 4) {
                int kn = k + 4 + e;
                int sn = sp[(kn <= kl) ? kn : kl];
                const unsigned short* np_ = xl + (size_t)sn * 256 + cb;
                u16x8 n0 = *(const u16x8*)(np_);
                u16x8 n1 = *(const u16x8*)(np_ + 8);

                float p = 0.f;
#pragma unroll
                for (int j = 0; j < 16; j++) {
                    float t = c[j] + rv[j];
                    t = (t > 0.f) ? t : 0.2f * t;
                    p = fmaf(t, av[j], p);
                }
                p += __shfl_xor(p, 1, 64);
                p += __shfl_xor(p, 2, 64);
                bool valid = (k + e) < ke;
                if (!valid) p = -3.0e38f;

                if (__any(p > m)) {  // rare after warmup
                    float nm = fmaxf(m, p);
                    float sc = __expf(m - nm);
                    d *= sc;
#pragma unroll
                    for (int j = 0; j < 16; j++) A[j] *= sc;
                    m = nm;
                }
                float wg = valid ? __expf(p - m) : 0.f;
                d += wg;
#pragma unroll
                for (int j = 0; j < 16; j++) A[j] = fmaf(wg, c[j], A[j]);

#pragma unroll
                for (int j = 0; j < 8; j++) { c[j] = bf2f(n0[j]); c[8 + j] = bf2f(n1[j]); }
            }
        }

        float M = fmaxf(m, __shfl_xor(m, 16, 64));
        M = fmaxf(M, __shfl_xor(M, 32, 64));
        float sc = __expf(m - M);
        d *= sc;
        d += __shfl_xor(d, 16, 64);
        d += __shfl_xor(d, 32, 64);
#pragma unroll
        for (int j = 0; j < 16; j++) {
            A[j] *= sc;
            A[j] += __shfl_xor(A[j], 16, 64);
            A[j] += __shfl_xor(A[j], 32, 64);
        }

        float inv = 1.0f / (d + 1e-16f);
        cv.x = fmaf(A[e * 4 + 0], inv, cv.x);
        cv.y = fmaf(A[e * 4 + 1], inv, cv.y);
        cv.z = fmaf(A[e * 4 + 2], inv, cv.z);
        cv.w = fmaf(A[e * 4 + 3], inv, cv.w);
    }

    // relu + split-bf16 pack into MFMA A-fragment layout (KT=8)
    cv.x = fmaxf(cv.x, 0.f);
    cv.y = fmaxf(cv.y, 0.f);
    cv.z = fmaxf(cv.z, 0.f);
    cv.w = fmaxf(cv.w, 0.f);
    float vv[4] = {cv.x, cv.y, cv.z, cv.w};
    bf16x4 hv, lv;
#pragma unroll
    for (int j = 0; j < 4; j++) {
        __bf16 h = (__bf16)vv[j];
        hv[j] = h;
        lv[j] = (__bf16)(vv[j] - (float)h);
    }
    size_t outp = (((size_t)(n >> 4) * 8 + (wc >> 5)) * 64 + ((wc >> 3) & 3) * 16 + (n & 15)) * 8 + (wc & 7);
    *(bf16x4*)(Ah + outp) = hv;
    *(bf16x4*)(Al + outp) = lv;
}

// ---------------- head ----------------

__global__ __launch_bounds__(256) void head_kernel(const float* __restrict__ hm,
                                                   const float* __restrict__ W2,
                                                   const float* __restrict__ b2,
                                                   float* __restrict__ out, int N) {
    int lane = threadIdx.x & 63;
    int wid = blockIdx.x * 4 + (threadIdx.x >> 6);
    if (wid >= N) return;
    int n = __builtin_amdgcn_readfirstlane(wid);
    float a0 = hm[(size_t)n * 128 + lane];
    float a1 = hm[(size_t)n * 128 + 64 + lane];
    float s0 = a0 * W2[lane * 3 + 0] + a1 * W2[(64 + lane) * 3 + 0];
    float s1 = a0 * W2[lane * 3 + 1] + a1 * W2[(64 + lane) * 3 + 1];
    float s2 = a0 * W2[lane * 3 + 2] + a1 * W2[(64 + lane) * 3 + 2];
#pragma unroll
    for (int sft = 1; sft < 64; sft <<= 1) {
        s0 += __shfl_xor(s0, sft, 64);
        s1 += __shfl_xor(s1, sft, 64);
        s2 += __shfl_xor(s2, sft, 64);
    }
    if (lane == 0) {
        out[(size_t)n * 3 + 0] = s0 + b2[0];
        out[(size_t)n * 3 + 1] = s1 + b2[1];
        out[(size_t)n * 3 + 2] = s2 + b2[2];
    }
}

// ---------------- launch ----------------

extern "C" void kernel_launch(void* const* d_in, const int* in_sizes, int n_in,
                              void* d_out, int out_size, void* d_ws, size_t ws_size,
                              hipStream_t stream) {
    const float* x    = (const float*)d_in[0];
    const int* date   = (const int*)d_in[1];
    const int* ei     = (const int*)d_in[2];
    const float* pW   = (const float*)d_in[3];
    const float* pb   = (const float*)d_in[4];
    const float* Wl0  = (const float*)d_in[5];
    const float* Wr0  = (const float*)d_in[6];
    const float* att0 = (const float*)d_in[7];
    const float* b0   = (const float*)d_in[8];
    const float* Wl1  = (const float*)d_in[9];
    const float* Wr1  = (const float*)d_in[10];
    const float* att1 = (const float*)d_in[11];
    const float* b1   = (const float*)d_in[12];
    // d_in[13..15] = aggW/aggb/agga — rel_agg is identity (h_rel broadcast), skipped
    const float* outW1 = (const float*)d_in[16];
    const float* outb1 = (const float*)d_in[17];
    const float* outW2 = (const float*)d_in[18];
    const float* outb2 = (const float*)d_in[19];
    float* out = (float*)d_out;

    int N = in_sizes[0] / 64;
    int E = in_sizes[2] / 10;
    int Mp = ((N + 127) / 128) * 128;
    int MT = Mp / 128;
    int MT8 = (MT + 7) / 8;  // bx octets
    int NC = (N + 1023) / 1024;

    char* ws = (char*)d_ws;
    size_t o = 0;
    auto alloc = [&](size_t bytes) -> char* {
        char* p = ws + o;
        o += (bytes + 255) & ~(size_t)255;
        return p;
    };
    int* cur               = (int*)alloc((size_t)5 * N * 4);
    int* csrOff            = (int*)alloc((size_t)5 * (N + 1) * 4);
    unsigned short* csrSrc = (unsigned short*)alloc((size_t)5 * E * 2);
    int* csums             = (int*)alloc((size_t)5 * NC * 4);
    unsigned short* xb16   = (unsigned short*)alloc((size_t)N * 64 * 2);
    float* h0              = (float*)alloc((size_t)N * 112 * 4);
    unsigned short* xl5    = (unsigned short*)alloc((size_t)5 * N * 256 * 2);
    unsigned short* xr5    = (unsigned short*)alloc((size_t)5 * N * 256 * 2);
    __bf16* Aph            = (__bf16*)alloc((size_t)Mp * 256 * 2);
    __bf16* Apl            = (__bf16*)alloc((size_t)Mp * 256 * 2);
    __bf16* Wph            = (__bf16*)alloc((size_t)1015808 * 2);
    __bf16* Wpl            = (__bf16*)alloc((size_t)1015808 * 2);
    float* hmid            = (float*)xl5;  // xl5 dead after layer-1 gat
    (void)ws_size;

    const size_t S0 = 32768, S1 = 65536;
    const size_t oWl0 = 0, oWr0 = 163840, oWl1 = 327680, oWr1 = 655360, oW1 = 983040;
    size_t xstride = (size_t)N * 256 * 2;

    int totE = 5 * E;

    // CSR by dst, per relation
    hipMemsetAsync(cur, 0, (size_t)5 * N * 4, stream);
    count_kernel<<<(totE + 255) / 256, 256, 0, stream>>>(ei, cur, N, E);
    scanA_kernel<<<dim3(NC, 5), 256, 0, stream>>>(cur, csrOff, csums, N, NC);
    scanB_kernel<<<1, 64, 0, stream>>>(csums, csrOff, N, NC);
    scanC_kernel<<<dim3(NC, 5), 256, 0, stream>>>(csrOff, csums, cur, N, NC);
    scatter_kernel<<<(totE + 255) / 256, 256, 0, stream>>>(ei, cur, csrSrc, N, E);

    // x -> bf16 copy + pearl PE + time PE + concat
    xcvt_kernel<<<(N * 64 / 4 + 255) / 256, 256, 0, stream>>>(x, xb16, N * 64);
    pearl_h0_kernel<<<(N + 3) / 4, 256, 0, stream>>>(x, xb16, date, csrOff, csrSrc, pW, pb, h0, N, E);

    // pack all weights (hi/lo split)
    pack_w_kernel<<<dim3(32, 21, 1), 256, 0, stream>>>(Wl0, Wr0, Wl1, Wr1, outW1, Wph, Wpl);

    // ----- layer 0 (K=112 -> Kp=128, KT=4) -----
    pack_a_kernel<<<(Mp * 16 + 255) / 256, 256, 0, stream>>>(h0, Aph, Apl, N, 112, Mp, 4);
    gemm_mfma<<<MT8 * 8 * 20, 256, 0, stream>>>(
        Aph, Apl, Wph + oWl0, Wpl + oWl0, Wph + oWr0, Wpl + oWr0, S0,
        xl5, xr5, xstride, N, 256, 4, nullptr, 0, 2, 1, 1, 2, MT, 20);
    gat5_kernel<<<(N + 7) / 8, 512, 0, stream>>>(xl5, xr5, att0, csrOff, csrSrc,
                                                 Aph, Apl, b0, N, E);

    // ----- layer 1 (K=256, KT=8) -----
    gemm_mfma<<<MT8 * 8 * 20, 256, 0, stream>>>(
        Aph, Apl, Wph + oWl1, Wpl + oWl1, Wph + oWr1, Wpl + oWr1, S1,
        xl5, xr5, xstride, N, 256, 8, nullptr, 0, 2, 1, 1, 2, MT, 20);
    gat5_kernel<<<(N + 7) / 8, 512, 0, stream>>>(xl5, xr5, att1, csrOff, csrSrc,
                                                 Aph, Apl, b1, N, E);

    // ----- MLP head: hmid = relu(packedA @ outW1 + outb1) -----
    gemm_mfma<<<MT8 * 8, 256, 0, stream>>>(
        Aph, Apl, Wph + oW1, Wpl + oW1, Wph + oW1, Wpl + oW1, 0,
        hmid, hmid, 0, N, 128, 8, outb1, 1, 3, 3, 0, 1, MT, 1);
    head_kernel<<<(N + 3) / 4, 256, 0, stream>>>(hmid, outW2, outb2, out, N);
}

// Round 13
// 749.864 us; speedup vs baseline: 1.0171x; 1.0171x over previous
//
#include <hip/hip_runtime.h>
#include <math.h>

typedef __bf16 bf16x8 __attribute__((ext_vector_type(8)));
typedef __bf16 bf16x4 __attribute__((ext_vector_type(4)));
typedef float f32x4 __attribute__((ext_vector_type(4)));
typedef unsigned short u16x8 __attribute__((ext_vector_type(8)));

#define GLD16(src, dst)                                                        \
    __builtin_amdgcn_global_load_lds(                                          \
        (const __attribute__((address_space(1))) void*)(src),                  \
        (__attribute__((address_space(3))) void*)(dst), 16, 0, 0)

__device__ inline float bf2f(unsigned short u) {
    union { unsigned int i; float f; } c;
    c.i = ((unsigned int)u) << 16;
    return c.f;
}

// ---------------- CSR build ----------------

__global__ __launch_bounds__(256) void count_kernel(const int* __restrict__ ei,
                                                    int* __restrict__ cnt, int N, int E) {
    int idx = blockIdx.x * 256 + threadIdx.x;
    if (idx >= 5 * E) return;
    int r = idx / E;
    int e = idx - r * E;
    int dst = ei[(size_t)r * 2 * E + E + e];
    atomicAdd(&cnt[r * N + dst], 1);
}

__global__ __launch_bounds__(256) void scanA_kernel(const int* __restrict__ cnt,
                                                    int* __restrict__ off,
                                                    int* __restrict__ csums, int N, int NC) {
    int r = blockIdx.y, c = blockIdx.x, t = threadIdx.x;
    int idx0 = c * 1024 + t * 4;
    int v0 = (idx0 + 0 < N) ? cnt[r * N + idx0 + 0] : 0;
    int v1 = (idx0 + 1 < N) ? cnt[r * N + idx0 + 1] : 0;
    int v2 = (idx0 + 2 < N) ? cnt[r * N + idx0 + 2] : 0;
    int v3 = (idx0 + 3 < N) ? cnt[r * N + idx0 + 3] : 0;
    int ts = v0 + v1 + v2 + v3;
    __shared__ int sd[256];
    sd[t] = ts;
    __syncthreads();
    for (int s = 1; s < 256; s <<= 1) {
        int add = (t >= s) ? sd[t - s] : 0;
        __syncthreads();
        sd[t] += add;
        __syncthreads();
    }
    int excl = sd[t] - ts;
    size_t base = (size_t)r * (N + 1);
    if (idx0 + 0 < N) off[base + idx0 + 0] = excl;
    if (idx0 + 1 < N) off[base + idx0 + 1] = excl + v0;
    if (idx0 + 2 < N) off[base + idx0 + 2] = excl + v0 + v1;
    if (idx0 + 3 < N) off[base + idx0 + 3] = excl + v0 + v1 + v2;
    if (t == 255) csums[r * NC + c] = sd[255];
}

__global__ __launch_bounds__(64) void scanB_kernel(int* __restrict__ csums,
                                                   int* __restrict__ off, int N, int NC) {
    int r = threadIdx.x;
    if (r < 5) {
        int run = 0;
        for (int c = 0; c < NC; c++) {
            int t = csums[r * NC + c];
            csums[r * NC + c] = run;
            run += t;
        }
        off[(size_t)r * (N + 1) + N] = run;
    }
}

__global__ __launch_bounds__(256) void scanC_kernel(int* __restrict__ off,
                                                    const int* __restrict__ csums,
                                                    int* __restrict__ cur,
                                                    int N, int NC) {
    int r = blockIdx.y, c = blockIdx.x, t = threadIdx.x;
    int add = csums[r * NC + c];
    int idx0 = c * 1024 + t * 4;
    size_t base = (size_t)r * (N + 1);
#pragma unroll
    for (int j = 0; j < 4; j++)
        if (idx0 + j < N) {
            int v = off[base + idx0 + j] + add;
            off[base + idx0 + j] = v;
            cur[r * N + idx0 + j] = v;
        }
}

__global__ __launch_bounds__(256) void scatter_kernel(const int* __restrict__ ei,
                                                      int* __restrict__ cur,
                                                      unsigned short* __restrict__ srcs,
                                                      int N, int E) {
    int idx = blockIdx.x * 256 + threadIdx.x;
    if (idx >= 5 * E) return;
    int r = idx / E;
    int e = idx - r * E;
    int src = ei[(size_t)r * 2 * E + e];
    int dst = ei[(size_t)r * 2 * E + E + e];
    int pos = atomicAdd(&cur[r * N + dst], 1);
    srcs[(size_t)r * E + pos] = (unsigned short)src;
}

// ---------------- x -> bf16 copy (for pearl gather) ----------------

__global__ __launch_bounds__(256) void xcvt_kernel(const float* __restrict__ x,
                                                   unsigned short* __restrict__ xb, int total) {
    int idx = (blockIdx.x * 256 + threadIdx.x) * 4;
    if (idx >= total) return;
    float4 v = *(const float4*)(x + idx);
    __bf16 b0 = (__bf16)v.x, b1 = (__bf16)v.y, b2 = (__bf16)v.z, b3 = (__bf16)v.w;
    unsigned short* p = xb + idx;
    p[0] = *(unsigned short*)&b0;
    p[1] = *(unsigned short*)&b1;
    p[2] = *(unsigned short*)&b2;
    p[3] = *(unsigned short*)&b3;
}

// ---------------- PEARL PE + time PE + concat -> h0 [N,112] ----------------
// lane = (parity p, channel-pair c): one u32 load = 2 bf16 channels of row
// k+2j+p -> one wave instruction covers 2 rows (256 B); parity-merge at end.

__global__ __launch_bounds__(256) void pearl_h0_kernel(
    const float* __restrict__ x, const unsigned short* __restrict__ xb,
    const int* __restrict__ date,
    const int* __restrict__ off, const unsigned short* __restrict__ srcs,
    const float* __restrict__ pW, const float* __restrict__ pb,
    float* __restrict__ h0, int N, int E) {
    int lane = threadIdx.x & 63;
    int wid = blockIdx.x * 4 + (threadIdx.x >> 6);
    if (wid >= N) return;
    int n = __builtin_amdgcn_readfirstlane(wid);
    int pr = lane >> 5;        // row parity
    int c2 = (lane & 31) * 2;  // channel base

    float a0 = 0.f, a1 = 0.f;
    int deg = 0;
    for (int r = 0; r < 5; r++) {
        int kb = off[(size_t)r * (N + 1) + n];
        int ke = off[(size_t)r * (N + 1) + n + 1];
        deg += ke - kb;
        const unsigned short* sp = srcs + (size_t)r * E;
        int k = kb;
        for (; k + 16 <= ke; k += 16) {
            unsigned int u[8];
#pragma unroll
            for (int j = 0; j < 8; j++) {
                int row = sp[k + 2 * j + pr];
                u[j] = *(const unsigned int*)(xb + (size_t)row * 64 + c2);
            }
#pragma unroll
            for (int j = 0; j < 8; j++) {
                a0 += bf2f((unsigned short)(u[j] & 0xffff));
                a1 += bf2f((unsigned short)(u[j] >> 16));
            }
        }
        for (; k + 2 <= ke; k += 2) {
            int row = sp[k + pr];
            unsigned int u = *(const unsigned int*)(xb + (size_t)row * 64 + c2);
            a0 += bf2f((unsigned short)(u & 0xffff));
            a1 += bf2f((unsigned short)(u >> 16));
        }
        if (k < ke) {  // odd tail: only parity-0 half contributes
            int row = sp[k];
            unsigned int u = *(const unsigned int*)(xb + (size_t)row * 64 + c2);
            if (pr == 0) {
                a0 += bf2f((unsigned short)(u & 0xffff));
                a1 += bf2f((unsigned short)(u >> 16));
            }
        }
    }
    a0 += __shfl_xor(a0, 32, 64);
    a1 += __shfl_xor(a1, 32, 64);
    float dn = fmaxf((float)deg, 1.0f);
    float an0 = a0 / dn, an1 = a1 / dn;

    float s = (lane < 32) ? pb[lane] : 0.f;
#pragma unroll
    for (int cc = 0; cc < 64; cc++) {
        float av = __shfl((cc & 1) ? an1 : an0, cc >> 1, 64);
        if (lane < 32) s = fmaf(av, pW[cc * 32 + lane], s);
    }

    h0[(size_t)n * 112 + lane] = x[(size_t)n * 64 + lane];
    if (lane < 32) h0[(size_t)n * 112 + 64 + lane] = tanhf(s);
    if (lane < 16) {
        float t = (float)date[n] / 10000.0f;
        int i = lane & 7;
        float dv = expf((float)(2 * i) * (-0.57564627324851148f));
        float arg = t * dv;
        h0[(size_t)n * 112 + 96 + lane] = (lane < 8) ? sinf(arg) : cosf(arg);
    }
}

// ---------------- pack A [M,K] fp32 -> hi/lo bf16, MFMA-fragment-major ----------------

__global__ __launch_bounds__(256) void pack_a_kernel(
    const float* __restrict__ A, __bf16* __restrict__ Ah, __bf16* __restrict__ Al,
    int M, int K, int Mp, int KT) {
    int KG = KT * 4;
    int idx = blockIdx.x * 256 + threadIdx.x;
    if (idx >= Mp * KG) return;
    int m = idx / KG, kgg = idx - m * KG;
    int kt = kgg >> 2, kg = kgg & 3;
    int k0 = kt * 32 + kg * 8;
    int mt = m >> 4, mr = m & 15;
    size_t out = (((size_t)mt * KT + kt) * 64 + kg * 16 + mr) * 8;
    bf16x8 hv, lv;
#pragma unroll
    for (int j = 0; j < 8; j++) {
        int k = k0 + j;
        float v = (m < M && k < K) ? A[(size_t)m * K + k] : 0.f;
        __bf16 h = (__bf16)v;
        hv[j] = h;
        lv[j] = (__bf16)(v - (float)h);
    }
    *(bf16x8*)(Ah + out) = hv;
    *(bf16x8*)(Al + out) = lv;
}

// ---------------- pack all weights (21 tensors, grid.y selects) ----------------

__global__ __launch_bounds__(256) void pack_w_kernel(
    const float* __restrict__ Wl0, const float* __restrict__ Wr0,
    const float* __restrict__ Wl1, const float* __restrict__ Wr1,
    const float* __restrict__ W1,
    __bf16* __restrict__ Wph, __bf16* __restrict__ Wpl) {
    const int S0 = 32768, S1 = 65536;
    int t = blockIdx.y;
    const float* W;
    int K, Nc, KT;
    size_t dst;
    if (t < 5)       { W = Wl0 + (size_t)t * 112 * 256;        K = 112; Nc = 256; KT = 4; dst = (size_t)t * S0; }
    else if (t < 10) { W = Wr0 + (size_t)(t - 5) * 112 * 256;  K = 112; Nc = 256; KT = 4; dst = 163840 + (size_t)(t - 5) * S0; }
    else if (t < 15) { W = Wl1 + (size_t)(t - 10) * 256 * 256; K = 256; Nc = 256; KT = 8; dst = 327680 + (size_t)(t - 10) * S1; }
    else if (t < 20) { W = Wr1 + (size_t)(t - 15) * 256 * 256; K = 256; Nc = 256; KT = 8; dst = 655360 + (size_t)(t - 15) * S1; }
    else             { W = W1;                                  K = 256; Nc = 128; KT = 8; dst = 983040; }
    int entries = (Nc / 16) * KT * 64;
    int idx = blockIdx.x * 256 + threadIdx.x;
    if (idx >= entries) return;
    int nt = idx / (KT * 64);
    int rem = idx - nt * (KT * 64);
    int kt = rem >> 6, lane = rem & 63;
    int kg = lane >> 4, nr = lane & 15;
    bf16x8 hv, lv;
#pragma unroll
    for (int j = 0; j < 8; j++) {
        int k = kt * 32 + kg * 8 + j;
        float v = (k < K) ? W[(size_t)k * Nc + nt * 16 + nr] : 0.f;
        __bf16 h = (__bf16)v;
        hv[j] = h;
        lv[j] = (__bf16)(v - (float)h);
    }
    *(bf16x8*)(Wph + dst + (size_t)idx * 8) = hv;
    *(bf16x8*)(Wpl + dst + (size_t)idx * 8) = lv;
}

// ---------------- split-bf16 MFMA GEMM, XCD-aware panel swizzle ----------------
// grid = ceil(MT/8)*8*NPANEL. p = g*(8*NPANEL) + panel*8 + slot: all NPANEL
// panels of one bx land on the same XCD (same p%8) -> A-tile fetched once/XCD.

__global__ __launch_bounds__(256) void gemm_mfma(
    const __bf16* __restrict__ Ah, const __bf16* __restrict__ Al,
    const __bf16* __restrict__ WLh, const __bf16* __restrict__ WLl,
    const __bf16* __restrict__ WRh, const __bf16* __restrict__ WRl,
    size_t strideB, void* __restrict__ Cl, void* __restrict__ Cr, size_t CstrideBytes,
    int M, int Nout, int KT, const float* __restrict__ bias, int do_relu,
    int npL, int npR, int out_bf16, int NYT, int MTp, int NPANEL) {
    int p = blockIdx.x;
    int stride = 8 * NPANEL;
    int g = p / stride, rem = p % stride;
    int slot = rem % 8, panel = rem / 8;
    int bx = g * 8 + slot;
    if (bx >= MTp) return;
    int by = panel % NYT;
    int side = (panel / NYT) & 1;
    int r = panel / (NYT * 2);

    const __bf16* Bh = (side ? WRh : WLh) + (size_t)r * strideB;
    const __bf16* Bl = (side ? WRl : WLl) + (size_t)r * strideB;
    char* C = (char*)(side ? Cr : Cl) + (size_t)r * CstrideBytes;
    int np = side ? npR : npL;

    __shared__ __bf16 sAh[8 * 512], sAl[8 * 512], sBh[8 * 512], sBl[8 * 512];

    int tid = threadIdx.x, lane = tid & 63, w = tid >> 6;
    int wr = w >> 1, wc = w & 1;

    f32x4 acc[4][4] = {};

    for (int kt = 0; kt < KT; ++kt) {
        int tl = w * 2;
        size_t a0 = ((size_t)(bx * 8 + tl) * KT + kt) * 512 + lane * 8;
        size_t a1 = ((size_t)(bx * 8 + tl + 1) * KT + kt) * 512 + lane * 8;
        size_t b0 = ((size_t)(by * 8 + tl) * KT + kt) * 512 + lane * 8;
        size_t b1 = ((size_t)(by * 8 + tl + 1) * KT + kt) * 512 + lane * 8;
        GLD16(Ah + a0, sAh + tl * 512);
        GLD16(Ah + a1, sAh + (tl + 1) * 512);
        GLD16(Bh + b0, sBh + tl * 512);
        GLD16(Bh + b1, sBh + (tl + 1) * 512);
        if (np >= 2) {
            GLD16(Al + a0, sAl + tl * 512);
            GLD16(Al + a1, sAl + (tl + 1) * 512);
        }
        if (np == 3) {
            GLD16(Bl + b0, sBl + tl * 512);
            GLD16(Bl + b1, sBl + (tl + 1) * 512);
        }
        __syncthreads();

        bf16x8 ah[4], al[4], bh[4], bl[4];
#pragma unroll
        for (int i = 0; i < 4; i++) {
            ah[i] = *(const bf16x8*)(sAh + (wr * 4 + i) * 512 + lane * 8);
            bh[i] = *(const bf16x8*)(sBh + (wc * 4 + i) * 512 + lane * 8);
        }
        if (np >= 2) {
#pragma unroll
            for (int i = 0; i < 4; i++)
                al[i] = *(const bf16x8*)(sAl + (wr * 4 + i) * 512 + lane * 8);
        }
        if (np == 3) {
#pragma unroll
            for (int i = 0; i < 4; i++)
                bl[i] = *(const bf16x8*)(sBl + (wc * 4 + i) * 512 + lane * 8);
        }
#pragma unroll
        for (int i = 0; i < 4; i++)
#pragma unroll
            for (int j = 0; j < 4; j++) {
                acc[i][j] = __builtin_amdgcn_mfma_f32_16x16x32_bf16(ah[i], bh[j], acc[i][j], 0, 0, 0);
                if (np >= 2)
                    acc[i][j] = __builtin_amdgcn_mfma_f32_16x16x32_bf16(al[i], bh[j], acc[i][j], 0, 0, 0);
                if (np == 3)
                    acc[i][j] = __builtin_amdgcn_mfma_f32_16x16x32_bf16(ah[i], bl[j], acc[i][j], 0, 0, 0);
            }
        __syncthreads();
    }

    int rb = bx * 128 + wr * 64, cb = by * 128 + wc * 64;
#pragma unroll
    for (int i = 0; i < 4; i++) {
#pragma unroll
        for (int j = 0; j < 4; j++) {
            int row0 = rb + i * 16 + (lane >> 4) * 4;
            int col = cb + j * 16 + (lane & 15);
            float bv = bias ? bias[col] : 0.f;
#pragma unroll
            for (int q = 0; q < 4; q++) {
                int row = row0 + q;
                if (row < M) {
                    float v = acc[i][j][q] + bv;
                    if (do_relu) v = fmaxf(v, 0.f);
                    if (out_bf16)
                        ((__bf16*)C)[(size_t)row * Nout + col] = (__bf16)v;
                    else
                        ((float*)C)[(size_t)row * Nout + col] = v;
                }
            }
        }
    }
}

// ---------------- fused GATv2 over ALL 5 relations (r7/r11 body, 4 waves) ----------------

__global__ __launch_bounds__(256) void gat5_kernel(
    const unsigned short* __restrict__ xl5, const unsigned short* __restrict__ xr5,
    const float* __restrict__ att,        // [5][256]
    const int* __restrict__ csrOff,       // [5][N+1]
    const unsigned short* __restrict__ csrSrc,  // [5][E]
    __bf16* __restrict__ Ah, __bf16* __restrict__ Al,  // packed output (KT=8)
    const float* __restrict__ bvec,       // [5][256]
    int N, int E) {
    int lane = threadIdx.x & 63;
    int wid = blockIdx.x * 4 + (threadIdx.x >> 6);
    if (wid >= N) return;
    int n = __builtin_amdgcn_readfirstlane(wid);
    int e = lane >> 4;
    int sub = lane & 15;
    int cb = (sub >> 2) * 64 + (sub & 3) * 16;  // head*64 + q*16
    int wc = cb + e * 4;

    float4 cv = {0.f, 0.f, 0.f, 0.f};
#pragma unroll
    for (int r = 0; r < 5; r++) {
        float4 b = *(const float4*)(bvec + r * 256 + wc);
        cv.x += b.x; cv.y += b.y; cv.z += b.z; cv.w += b.w;
    }

    for (int r = 0; r < 5; r++) {
        const unsigned short* xl = xl5 + (size_t)r * N * 256;
        float rv[16], av[16];
        {
            const unsigned short* xrp = xr5 + ((size_t)r * N + n) * 256 + cb;
            u16x8 q0 = *(const u16x8*)(xrp);
            u16x8 q1 = *(const u16x8*)(xrp + 8);
#pragma unroll
            for (int j = 0; j < 8; j++) { rv[j] = bf2f(q0[j]); rv[8 + j] = bf2f(q1[j]); }
#pragma unroll
            for (int j = 0; j < 16; j += 4) {
                float4 a = *(const float4*)(att + r * 256 + cb + j);
                av[j] = a.x; av[j + 1] = a.y; av[j + 2] = a.z; av[j + 3] = a.w;
            }
        }

        float m = -3.0e38f, d = 0.f;
        float A[16];
#pragma unroll
        for (int j = 0; j < 16; j++) A[j] = 0.f;

        const int* off = csrOff + (size_t)r * (N + 1);
        const unsigned short* sp = csrSrc + (size_t)r * E;
        int kb = off[n], ke = off[n + 1];
        if (kb < ke) {
            int kl = ke - 1;
            int ki = kb + e;
            int s = sp[(ki <= kl) ? ki : kl];
            float c[16];
            {
                const unsigned short* xp = xl + (size_t)s * 256 + cb;
                u16x8 q0 = *(const u16x8*)(xp);
                u16x8 q1 = *(const u16x8*)(xp + 8);
#pragma unroll
                for (int j = 0; j < 8; j++) { c[j] = bf2f(q0[j]); c[8 + j] = bf2f(q1[j]); }
            }
            for (int k = kb; k < ke; k += 4) {
                int kn = k + 4 + e;
                int sn = sp[(kn <= kl) ? kn : kl];
                const unsigned short* np_ = xl + (size_t)sn * 256 + cb;
                u16x8 n0 = *(const u16x8*)(np_);
                u16x8 n1 = *(const u16x8*)(np_ + 8);

                float p = 0.f;
#pragma unroll
                for (int j = 0; j < 16; j++) {
                    float t = c[j] + rv[j];
                    t = (t > 0.f) ? t : 0.2f * t;
                    p = fmaf(t, av[j], p);
                }
                p += __shfl_xor(p, 1, 64);
                p += __shfl_xor(p, 2, 64);
                bool valid = (k + e) < ke;
                if (!valid) p = -3.0e38f;

                if (__any(p > m)) {  // rare after warmup
                    float nm = fmaxf(m, p);
                    float sc = __expf(m - nm);
                    d *= sc;
#pragma unroll
                    for (int j = 0; j < 16; j++) A[j] *= sc;
                    m = nm;
                }
                float wg = valid ? __expf(p - m) : 0.f;
                d += wg;
#pragma unroll
                for (int j = 0; j < 16; j++) A[j] = fmaf(wg, c[j], A[j]);

#pragma unroll
                for (int j = 0; j < 8; j++) { c[j] = bf2f(n0[j]); c[8 + j] = bf2f(n1[j]); }
            }
        }

        float M = fmaxf(m, __shfl_xor(m, 16, 64));
        M = fmaxf(M, __shfl_xor(M, 32, 64));
        float sc = __expf(m - M);
        d *= sc;
        d += __shfl_xor(d, 16, 64);
        d += __shfl_xor(d, 32, 64);
#pragma unroll
        for (int j = 0; j < 16; j++) {
            A[j] *= sc;
            A[j] += __shfl_xor(A[j], 16, 64);
            A[j] += __shfl_xor(A[j], 32, 64);
        }

        float inv = 1.0f / (d + 1e-16f);
        cv.x = fmaf(A[e * 4 + 0], inv, cv.x);
        cv.y = fmaf(A[e * 4 + 1], inv, cv.y);
        cv.z = fmaf(A[e * 4 + 2], inv, cv.z);
        cv.w = fmaf(A[e * 4 + 3], inv, cv.w);
    }

    // relu + split-bf16 pack into MFMA A-fragment layout (KT=8)
    cv.x = fmaxf(cv.x, 0.f);
    cv.y = fmaxf(cv.y, 0.f);
    cv.z = fmaxf(cv.z, 0.f);
    cv.w = fmaxf(cv.w, 0.f);
    float vv[4] = {cv.x, cv.y, cv.z, cv.w};
    bf16x4 hv, lv;
#pragma unroll
    for (int j = 0; j < 4; j++) {
        __bf16 h = (__bf16)vv[j];
        hv[j] = h;
        lv[j] = (__bf16)(vv[j] - (float)h);
    }
    size_t outp = (((size_t)(n >> 4) * 8 + (wc >> 5)) * 64 + ((wc >> 3) & 3) * 16 + (n & 15)) * 8 + (wc & 7);
    *(bf16x4*)(Ah + outp) = hv;
    *(bf16x4*)(Al + outp) = lv;
}

// ---------------- head ----------------

__global__ __launch_bounds__(256) void head_kernel(const float* __restrict__ hm,
                                                   const float* __restrict__ W2,
                                                   const float* __restrict__ b2,
                                                   float* __restrict__ out, int N) {
    int lane = threadIdx.x & 63;
    int wid = blockIdx.x * 4 + (threadIdx.x >> 6);
    if (wid >= N) return;
    int n = __builtin_amdgcn_readfirstlane(wid);
    float a0 = hm[(size_t)n * 128 + lane];
    float a1 = hm[(size_t)n * 128 + 64 + lane];
    float s0 = a0 * W2[lane * 3 + 0] + a1 * W2[(64 + lane) * 3 + 0];
    float s1 = a0 * W2[lane * 3 + 1] + a1 * W2[(64 + lane) * 3 + 1];
    float s2 = a0 * W2[lane * 3 + 2] + a1 * W2[(64 + lane) * 3 + 2];
#pragma unroll
    for (int sft = 1; sft < 64; sft <<= 1) {
        s0 += __shfl_xor(s0, sft, 64);
        s1 += __shfl_xor(s1, sft, 64);
        s2 += __shfl_xor(s2, sft, 64);
    }
    if (lane == 0) {
        out[(size_t)n * 3 + 0] = s0 + b2[0];
        out[(size_t)n * 3 + 1] = s1 + b2[1];
        out[(size_t)n * 3 + 2] = s2 + b2[2];
    }
}

// ---------------- launch ----------------

extern "C" void kernel_launch(void* const* d_in, const int* in_sizes, int n_in,
                              void* d_out, int out_size, void* d_ws, size_t ws_size,
                              hipStream_t stream) {
    const float* x    = (const float*)d_in[0];
    const int* date   = (const int*)d_in[1];
    const int* ei     = (const int*)d_in[2];
    const float* pW   = (const float*)d_in[3];
    const float* pb   = (const float*)d_in[4];
    const float* Wl0  = (const float*)d_in[5];
    const float* Wr0  = (const float*)d_in[6];
    const float* att0 = (const float*)d_in[7];
    const float* b0   = (const float*)d_in[8];
    const float* Wl1  = (const float*)d_in[9];
    const float* Wr1  = (const float*)d_in[10];
    const float* att1 = (const float*)d_in[11];
    const float* b1   = (const float*)d_in[12];
    // d_in[13..15] = aggW/aggb/agga — rel_agg is identity (h_rel broadcast), skipped
    const float* outW1 = (const float*)d_in[16];
    const float* outb1 = (const float*)d_in[17];
    const float* outW2 = (const float*)d_in[18];
    const float* outb2 = (const float*)d_in[19];
    float* out = (float*)d_out;

    int N = in_sizes[0] / 64;
    int E = in_sizes[2] / 10;
    int Mp = ((N + 127) / 128) * 128;
    int MT = Mp / 128;
    int MT8 = (MT + 7) / 8;  // bx octets
    int NC = (N + 1023) / 1024;

    char* ws = (char*)d_ws;
    size_t o = 0;
    auto alloc = [&](size_t bytes) -> char* {
        char* p = ws + o;
        o += (bytes + 255) & ~(size_t)255;
        return p;
    };
    int* cur               = (int*)alloc((size_t)5 * N * 4);
    int* csrOff            = (int*)alloc((size_t)5 * (N + 1) * 4);
    unsigned short* csrSrc = (unsigned short*)alloc((size_t)5 * E * 2);
    int* csums             = (int*)alloc((size_t)5 * NC * 4);
    unsigned short* xb16   = (unsigned short*)alloc((size_t)N * 64 * 2);
    float* h0              = (float*)alloc((size_t)N * 112 * 4);
    unsigned short* xl5    = (unsigned short*)alloc((size_t)5 * N * 256 * 2);
    unsigned short* xr5    = (unsigned short*)alloc((size_t)5 * N * 256 * 2);
    __bf16* Aph            = (__bf16*)alloc((size_t)Mp * 256 * 2);
    __bf16* Apl            = (__bf16*)alloc((size_t)Mp * 256 * 2);
    __bf16* Wph            = (__bf16*)alloc((size_t)1015808 * 2);
    __bf16* Wpl            = (__bf16*)alloc((size_t)1015808 * 2);
    float* hmid            = (float*)xl5;  // xl5 dead after layer-1 gat
    (void)ws_size;

    const size_t S0 = 32768, S1 = 65536;
    const size_t oWl0 = 0, oWr0 = 163840, oWl1 = 327680, oWr1 = 655360, oW1 = 983040;
    size_t xstride = (size_t)N * 256 * 2;

    int totE = 5 * E;

    // CSR by dst, per relation
    hipMemsetAsync(cur, 0, (size_t)5 * N * 4, stream);
    count_kernel<<<(totE + 255) / 256, 256, 0, stream>>>(ei, cur, N, E);
    scanA_kernel<<<dim3(NC, 5), 256, 0, stream>>>(cur, csrOff, csums, N, NC);
    scanB_kernel<<<1, 64, 0, stream>>>(csums, csrOff, N, NC);
    scanC_kernel<<<dim3(NC, 5), 256, 0, stream>>>(csrOff, csums, cur, N, NC);
    scatter_kernel<<<(totE + 255) / 256, 256, 0, stream>>>(ei, cur, csrSrc, N, E);

    // x -> bf16 copy + pearl PE + time PE + concat
    xcvt_kernel<<<(N * 64 / 4 + 255) / 256, 256, 0, stream>>>(x, xb16, N * 64);
    pearl_h0_kernel<<<(N + 3) / 4, 256, 0, stream>>>(x, xb16, date, csrOff, csrSrc, pW, pb, h0, N, E);

    // pack all weights (hi/lo split)
    pack_w_kernel<<<dim3(32, 21, 1), 256, 0, stream>>>(Wl0, Wr0, Wl1, Wr1, outW1, Wph, Wpl);

    // ----- layer 0 (K=112 -> Kp=128, KT=4): npL=1 (AhBh only; error ~bf16 storage) -----
    pack_a_kernel<<<(Mp * 16 + 255) / 256, 256, 0, stream>>>(h0, Aph, Apl, N, 112, Mp, 4);
    gemm_mfma<<<MT8 * 8 * 20, 256, 0, stream>>>(
        Aph, Apl, Wph + oWl0, Wpl + oWl0, Wph + oWr0, Wpl + oWr0, S0,
        xl5, xr5, xstride, N, 256, 4, nullptr, 0, 1, 1, 1, 2, MT, 20);
    gat5_kernel<<<(N + 3) / 4, 256, 0, stream>>>(xl5, xr5, att0, csrOff, csrSrc,
                                                 Aph, Apl, b0, N, E);

    // ----- layer 1 (K=256, KT=8): npL=1 -----
    gemm_mfma<<<MT8 * 8 * 20, 256, 0, stream>>>(
        Aph, Apl, Wph + oWl1, Wpl + oWl1, Wph + oWr1, Wpl + oWr1, S1,
        xl5, xr5, xstride, N, 256, 8, nullptr, 0, 1, 1, 1, 2, MT, 20);
    gat5_kernel<<<(N + 3) / 4, 256, 0, stream>>>(xl5, xr5, att1, csrOff, csrSrc,
                                                 Aph, Apl, b1, N, E);

    // ----- MLP head: hmid = relu(packedA @ outW1 + outb1), full 3-pass -----
    gemm_mfma<<<MT8 * 8, 256, 0, stream>>>(
        Aph, Apl, Wph + oW1, Wpl + oW1, Wph + oW1, Wpl + oW1, 0,
        hmid, hmid, 0, N, 128, 8, outb1, 1, 3, 3, 0, 1, MT, 1);
    head_kernel<<<(N + 3) / 4, 256, 0, stream>>>(hmid, outW2, outb2, out, N);
}

// Round 14
// 747.656 us; speedup vs baseline: 1.0201x; 1.0030x over previous
//
#include <hip/hip_runtime.h>
#include <math.h>

typedef __bf16 bf16x8 __attribute__((ext_vector_type(8)));
typedef __bf16 bf16x4 __attribute__((ext_vector_type(4)));
typedef float f32x4 __attribute__((ext_vector_type(4)));
typedef unsigned short u16x8 __attribute__((ext_vector_type(8)));

#define GLD16(src, dst)                                                        \
    __builtin_amdgcn_global_load_lds(                                          \
        (const __attribute__((address_space(1))) void*)(src),                  \
        (__attribute__((address_space(3))) void*)(dst), 16, 0, 0)

__device__ inline float bf2f(unsigned short u) {
    union { unsigned int i; float f; } c;
    c.i = ((unsigned int)u) << 16;
    return c.f;
}

// ---------------- CSR build ----------------

__global__ __launch_bounds__(256) void count_kernel(const int* __restrict__ ei,
                                                    int* __restrict__ cnt, int N, int E) {
    int idx = blockIdx.x * 256 + threadIdx.x;
    if (idx >= 5 * E) return;
    int r = idx / E;
    int e = idx - r * E;
    int dst = ei[(size_t)r * 2 * E + E + e];
    atomicAdd(&cnt[r * N + dst], 1);
}

__global__ __launch_bounds__(256) void scanA_kernel(const int* __restrict__ cnt,
                                                    int* __restrict__ off,
                                                    int* __restrict__ csums, int N, int NC) {
    int r = blockIdx.y, c = blockIdx.x, t = threadIdx.x;
    int idx0 = c * 1024 + t * 4;
    int v0 = (idx0 + 0 < N) ? cnt[r * N + idx0 + 0] : 0;
    int v1 = (idx0 + 1 < N) ? cnt[r * N + idx0 + 1] : 0;
    int v2 = (idx0 + 2 < N) ? cnt[r * N + idx0 + 2] : 0;
    int v3 = (idx0 + 3 < N) ? cnt[r * N + idx0 + 3] : 0;
    int ts = v0 + v1 + v2 + v3;
    __shared__ int sd[256];
    sd[t] = ts;
    __syncthreads();
    for (int s = 1; s < 256; s <<= 1) {
        int add = (t >= s) ? sd[t - s] : 0;
        __syncthreads();
        sd[t] += add;
        __syncthreads();
    }
    int excl = sd[t] - ts;
    size_t base = (size_t)r * (N + 1);
    if (idx0 + 0 < N) off[base + idx0 + 0] = excl;
    if (idx0 + 1 < N) off[base + idx0 + 1] = excl + v0;
    if (idx0 + 2 < N) off[base + idx0 + 2] = excl + v0 + v1;
    if (idx0 + 3 < N) off[base + idx0 + 3] = excl + v0 + v1 + v2;
    if (t == 255) csums[r * NC + c] = sd[255];
}

__global__ __launch_bounds__(64) void scanB_kernel(int* __restrict__ csums,
                                                   int* __restrict__ off, int N, int NC) {
    int r = threadIdx.x;
    if (r < 5) {
        int run = 0;
        for (int c = 0; c < NC; c++) {
            int t = csums[r * NC + c];
            csums[r * NC + c] = run;
            run += t;
        }
        off[(size_t)r * (N + 1) + N] = run;
    }
}

__global__ __launch_bounds__(256) void scanC_kernel(int* __restrict__ off,
                                                    const int* __restrict__ csums,
                                                    int* __restrict__ cur,
                                                    int N, int NC) {
    int r = blockIdx.y, c = blockIdx.x, t = threadIdx.x;
    int add = csums[r * NC + c];
    int idx0 = c * 1024 + t * 4;
    size_t base = (size_t)r * (N + 1);
#pragma unroll
    for (int j = 0; j < 4; j++)
        if (idx0 + j < N) {
            int v = off[base + idx0 + j] + add;
            off[base + idx0 + j] = v;
            cur[r * N + idx0 + j] = v;
        }
}

__global__ __launch_bounds__(256) void scatter_kernel(const int* __restrict__ ei,
                                                      int* __restrict__ cur,
                                                      unsigned short* __restrict__ srcs,
                                                      int N, int E) {
    int idx = blockIdx.x * 256 + threadIdx.x;
    if (idx >= 5 * E) return;
    int r = idx / E;
    int e = idx - r * E;
    int src = ei[(size_t)r * 2 * E + e];
    int dst = ei[(size_t)r * 2 * E + E + e];
    int pos = atomicAdd(&cur[r * N + dst], 1);
    srcs[(size_t)r * E + pos] = (unsigned short)src;
}

// ---------------- x -> bf16 copy (for pearl gather) ----------------

__global__ __launch_bounds__(256) void xcvt_kernel(const float* __restrict__ x,
                                                   unsigned short* __restrict__ xb, int total) {
    int idx = (blockIdx.x * 256 + threadIdx.x) * 4;
    if (idx >= total) return;
    float4 v = *(const float4*)(x + idx);
    __bf16 b0 = (__bf16)v.x, b1 = (__bf16)v.y, b2 = (__bf16)v.z, b3 = (__bf16)v.w;
    unsigned short* p = xb + idx;
    p[0] = *(unsigned short*)&b0;
    p[1] = *(unsigned short*)&b1;
    p[2] = *(unsigned short*)&b2;
    p[3] = *(unsigned short*)&b3;
}

// ---------------- PEARL PE + time PE + concat -> h0 [N,112] ----------------

__global__ __launch_bounds__(256) void pearl_h0_kernel(
    const float* __restrict__ x, const unsigned short* __restrict__ xb,
    const int* __restrict__ date,
    const int* __restrict__ off, const unsigned short* __restrict__ srcs,
    const float* __restrict__ pW, const float* __restrict__ pb,
    float* __restrict__ h0, int N, int E) {
    int lane = threadIdx.x & 63;
    int wid = blockIdx.x * 4 + (threadIdx.x >> 6);
    if (wid >= N) return;
    int n = __builtin_amdgcn_readfirstlane(wid);
    int pr = lane >> 5;        // row parity
    int c2 = (lane & 31) * 2;  // channel base

    float a0 = 0.f, a1 = 0.f;
    int deg = 0;
    for (int r = 0; r < 5; r++) {
        int kb = off[(size_t)r * (N + 1) + n];
        int ke = off[(size_t)r * (N + 1) + n + 1];
        deg += ke - kb;
        const unsigned short* sp = srcs + (size_t)r * E;
        int k = kb;
        for (; k + 16 <= ke; k += 16) {
            unsigned int u[8];
#pragma unroll
            for (int j = 0; j < 8; j++) {
                int row = sp[k + 2 * j + pr];
                u[j] = *(const unsigned int*)(xb + (size_t)row * 64 + c2);
            }
#pragma unroll
            for (int j = 0; j < 8; j++) {
                a0 += bf2f((unsigned short)(u[j] & 0xffff));
                a1 += bf2f((unsigned short)(u[j] >> 16));
            }
        }
        for (; k + 2 <= ke; k += 2) {
            int row = sp[k + pr];
            unsigned int u = *(const unsigned int*)(xb + (size_t)row * 64 + c2);
            a0 += bf2f((unsigned short)(u & 0xffff));
            a1 += bf2f((unsigned short)(u >> 16));
        }
        if (k < ke) {
            int row = sp[k];
            unsigned int u = *(const unsigned int*)(xb + (size_t)row * 64 + c2);
            if (pr == 0) {
                a0 += bf2f((unsigned short)(u & 0xffff));
                a1 += bf2f((unsigned short)(u >> 16));
            }
        }
    }
    a0 += __shfl_xor(a0, 32, 64);
    a1 += __shfl_xor(a1, 32, 64);
    float dn = fmaxf((float)deg, 1.0f);
    float an0 = a0 / dn, an1 = a1 / dn;

    float s = (lane < 32) ? pb[lane] : 0.f;
#pragma unroll
    for (int cc = 0; cc < 64; cc++) {
        float av = __shfl((cc & 1) ? an1 : an0, cc >> 1, 64);
        if (lane < 32) s = fmaf(av, pW[cc * 32 + lane], s);
    }

    h0[(size_t)n * 112 + lane] = x[(size_t)n * 64 + lane];
    if (lane < 32) h0[(size_t)n * 112 + 64 + lane] = tanhf(s);
    if (lane < 16) {
        float t = (float)date[n] / 10000.0f;
        int i = lane & 7;
        float dv = expf((float)(2 * i) * (-0.57564627324851148f));
        float arg = t * dv;
        h0[(size_t)n * 112 + 96 + lane] = (lane < 8) ? sinf(arg) : cosf(arg);
    }
}

// ---------------- pack A [M,K] fp32 -> hi(/lo) bf16, MFMA-fragment-major ----------------

__global__ __launch_bounds__(256) void pack_a_kernel(
    const float* __restrict__ A, __bf16* __restrict__ Ah, __bf16* __restrict__ Al,
    int M, int K, int Mp, int KT, int write_lo) {
    int KG = KT * 4;
    int idx = blockIdx.x * 256 + threadIdx.x;
    if (idx >= Mp * KG) return;
    int m = idx / KG, kgg = idx - m * KG;
    int kt = kgg >> 2, kg = kgg & 3;
    int k0 = kt * 32 + kg * 8;
    int mt = m >> 4, mr = m & 15;
    size_t out = (((size_t)mt * KT + kt) * 64 + kg * 16 + mr) * 8;
    bf16x8 hv, lv;
#pragma unroll
    for (int j = 0; j < 8; j++) {
        int k = k0 + j;
        float v = (m < M && k < K) ? A[(size_t)m * K + k] : 0.f;
        __bf16 h = (__bf16)v;
        hv[j] = h;
        lv[j] = (__bf16)(v - (float)h);
    }
    *(bf16x8*)(Ah + out) = hv;
    if (write_lo) *(bf16x8*)(Al + out) = lv;
}

// ---------------- pack all weights; lo only for head W1 (t==20) ----------------

__global__ __launch_bounds__(256) void pack_w_kernel(
    const float* __restrict__ Wl0, const float* __restrict__ Wr0,
    const float* __restrict__ Wl1, const float* __restrict__ Wr1,
    const float* __restrict__ W1,
    __bf16* __restrict__ Wph, __bf16* __restrict__ Wpl) {
    const int S0 = 32768, S1 = 65536;
    int t = blockIdx.y;
    const float* W;
    int K, Nc, KT;
    size_t dst;
    if (t < 5)       { W = Wl0 + (size_t)t * 112 * 256;        K = 112; Nc = 256; KT = 4; dst = (size_t)t * S0; }
    else if (t < 10) { W = Wr0 + (size_t)(t - 5) * 112 * 256;  K = 112; Nc = 256; KT = 4; dst = 163840 + (size_t)(t - 5) * S0; }
    else if (t < 15) { W = Wl1 + (size_t)(t - 10) * 256 * 256; K = 256; Nc = 256; KT = 8; dst = 327680 + (size_t)(t - 10) * S1; }
    else if (t < 20) { W = Wr1 + (size_t)(t - 15) * 256 * 256; K = 256; Nc = 256; KT = 8; dst = 655360 + (size_t)(t - 15) * S1; }
    else             { W = W1;                                  K = 256; Nc = 128; KT = 8; dst = 983040; }
    int entries = (Nc / 16) * KT * 64;
    int idx = blockIdx.x * 256 + threadIdx.x;
    if (idx >= entries) return;
    int nt = idx / (KT * 64);
    int rem = idx - nt * (KT * 64);
    int kt = rem >> 6, lane = rem & 63;
    int kg = lane >> 4, nr = lane & 15;
    bf16x8 hv, lv;
#pragma unroll
    for (int j = 0; j < 8; j++) {
        int k = kt * 32 + kg * 8 + j;
        float v = (k < K) ? W[(size_t)k * Nc + nt * 16 + nr] : 0.f;
        __bf16 h = (__bf16)v;
        hv[j] = h;
        lv[j] = (__bf16)(v - (float)h);
    }
    *(bf16x8*)(Wph + dst + (size_t)idx * 8) = hv;
    if (t == 20) *(bf16x8*)(Wpl + dst + (size_t)idx * 8) = lv;
}

// ---------------- split-bf16 MFMA GEMM, XCD panel swizzle, kstep k-tiles/barrier ----------------
// Dynamic LDS 32 KB: kstep=2 (np=1): sA[2][4096] | sB[2][4096].
//                    kstep=1 (np=3): sA[4096] sAl[4096] | sB[4096] sBl[4096].

__global__ __launch_bounds__(256) void gemm_mfma(
    const __bf16* __restrict__ Ah, const __bf16* __restrict__ Al,
    const __bf16* __restrict__ WLh, const __bf16* __restrict__ WLl,
    const __bf16* __restrict__ WRh, const __bf16* __restrict__ WRl,
    size_t strideB, void* __restrict__ Cl, void* __restrict__ Cr, size_t CstrideBytes,
    int M, int Nout, int KT, const float* __restrict__ bias, int do_relu,
    int npL, int npR, int out_bf16, int NYT, int MTp, int NPANEL, int kstep) {
    extern __shared__ __bf16 smem[];
    __bf16* sA = smem;            // kk*4096
    __bf16* sAl_ = smem + 4096;   // kstep==1, np>=2 only
    __bf16* sB = smem + 8192;     // kk*4096
    __bf16* sBl_ = smem + 12288;  // kstep==1, np==3 only

    int p = blockIdx.x;
    int stride = 8 * NPANEL;
    int g = p / stride, rem = p % stride;
    int slot = rem % 8, panel = rem / 8;
    int bx = g * 8 + slot;
    if (bx >= MTp) return;
    int by = panel % NYT;
    int side = (panel / NYT) & 1;
    int r = panel / (NYT * 2);

    const __bf16* Bh = (side ? WRh : WLh) + (size_t)r * strideB;
    const __bf16* Bl = (side ? WRl : WLl) + (size_t)r * strideB;
    char* C = (char*)(side ? Cr : Cl) + (size_t)r * CstrideBytes;
    int np = side ? npR : npL;

    int tid = threadIdx.x, lane = tid & 63, w = tid >> 6;
    int wr = w >> 1, wc = w & 1;
    int tl = w * 2;

    f32x4 acc[4][4] = {};

    for (int kt = 0; kt < KT; kt += kstep) {
        for (int kk = 0; kk < kstep; kk++) {
            int ktc = kt + kk;
            size_t a0 = ((size_t)(bx * 8 + tl) * KT + ktc) * 512 + lane * 8;
            size_t a1 = ((size_t)(bx * 8 + tl + 1) * KT + ktc) * 512 + lane * 8;
            size_t b0 = ((size_t)(by * 8 + tl) * KT + ktc) * 512 + lane * 8;
            size_t b1 = ((size_t)(by * 8 + tl + 1) * KT + ktc) * 512 + lane * 8;
            GLD16(Ah + a0, sA + kk * 4096 + tl * 512);
            GLD16(Ah + a1, sA + kk * 4096 + (tl + 1) * 512);
            GLD16(Bh + b0, sB + kk * 4096 + tl * 512);
            GLD16(Bh + b1, sB + kk * 4096 + (tl + 1) * 512);
            if (np >= 2) {
                GLD16(Al + a0, sAl_ + tl * 512);
                GLD16(Al + a1, sAl_ + (tl + 1) * 512);
            }
            if (np == 3) {
                GLD16(Bl + b0, sBl_ + tl * 512);
                GLD16(Bl + b1, sBl_ + (tl + 1) * 512);
            }
        }
        __syncthreads();

        for (int kk = 0; kk < kstep; kk++) {
            bf16x8 ah[4], al[4], bh[4], bl[4];
#pragma unroll
            for (int i = 0; i < 4; i++) {
                ah[i] = *(const bf16x8*)(sA + kk * 4096 + (wr * 4 + i) * 512 + lane * 8);
                bh[i] = *(const bf16x8*)(sB + kk * 4096 + (wc * 4 + i) * 512 + lane * 8);
            }
            if (np >= 2) {
#pragma unroll
                for (int i = 0; i < 4; i++)
                    al[i] = *(const bf16x8*)(sAl_ + (wr * 4 + i) * 512 + lane * 8);
            }
            if (np == 3) {
#pragma unroll
                for (int i = 0; i < 4; i++)
                    bl[i] = *(const bf16x8*)(sBl_ + (wc * 4 + i) * 512 + lane * 8);
            }
#pragma unroll
            for (int i = 0; i < 4; i++)
#pragma unroll
                for (int j = 0; j < 4; j++) {
                    acc[i][j] = __builtin_amdgcn_mfma_f32_16x16x32_bf16(ah[i], bh[j], acc[i][j], 0, 0, 0);
                    if (np >= 2)
                        acc[i][j] = __builtin_amdgcn_mfma_f32_16x16x32_bf16(al[i], bh[j], acc[i][j], 0, 0, 0);
                    if (np == 3)
                        acc[i][j] = __builtin_amdgcn_mfma_f32_16x16x32_bf16(ah[i], bl[j], acc[i][j], 0, 0, 0);
                }
        }
        __syncthreads();
    }

    int rb = bx * 128 + wr * 64, cb = by * 128 + wc * 64;
#pragma unroll
    for (int i = 0; i < 4; i++) {
#pragma unroll
        for (int j = 0; j < 4; j++) {
            int row0 = rb + i * 16 + (lane >> 4) * 4;
            int col = cb + j * 16 + (lane & 15);
            float bv = bias ? bias[col] : 0.f;
#pragma unroll
            for (int q = 0; q < 4; q++) {
                int row = row0 + q;
                if (row < M) {
                    float v = acc[i][j][q] + bv;
                    if (do_relu) v = fmaxf(v, 0.f);
                    if (out_bf16)
                        ((__bf16*)C)[(size_t)row * Nout + col] = (__bf16)v;
                    else
                        ((float*)C)[(size_t)row * Nout + col] = v;
                }
            }
        }
    }
}

// ---------------- fused GATv2 over ALL 5 relations (r7/r11 body) ----------------

__global__ __launch_bounds__(256) void gat5_kernel(
    const unsigned short* __restrict__ xl5, const unsigned short* __restrict__ xr5,
    const float* __restrict__ att,        // [5][256]
    const int* __restrict__ csrOff,       // [5][N+1]
    const unsigned short* __restrict__ csrSrc,  // [5][E]
    __bf16* __restrict__ Ah, __bf16* __restrict__ Al,  // packed output (KT=8)
    const float* __restrict__ bvec,       // [5][256]
    int N, int E, int write_lo) {
    int lane = threadIdx.x & 63;
    int wid = blockIdx.x * 4 + (threadIdx.x >> 6);
    if (wid >= N) return;
    int n = __builtin_amdgcn_readfirstlane(wid);
    int e = lane >> 4;
    int sub = lane & 15;
    int cb = (sub >> 2) * 64 + (sub & 3) * 16;  // head*64 + q*16
    int wc = cb + e * 4;

    float4 cv = {0.f, 0.f, 0.f, 0.f};
#pragma unroll
    for (int r = 0; r < 5; r++) {
        float4 b = *(const float4*)(bvec + r * 256 + wc);
        cv.x += b.x; cv.y += b.y; cv.z += b.z; cv.w += b.w;
    }

    for (int r = 0; r < 5; r++) {
        const unsigned short* xl = xl5 + (size_t)r * N * 256;
        float rv[16], av[16];
        {
            const unsigned short* xrp = xr5 + ((size_t)r * N + n) * 256 + cb;
            u16x8 q0 = *(const u16x8*)(xrp);
            u16x8 q1 = *(const u16x8*)(xrp + 8);
#pragma unroll
            for (int j = 0; j < 8; j++) { rv[j] = bf2f(q0[j]); rv[8 + j] = bf2f(q1[j]); }
#pragma unroll
            for (int j = 0; j < 16; j += 4) {
                float4 a = *(const float4*)(att + r * 256 + cb + j);
                av[j] = a.x; av[j + 1] = a.y; av[j + 2] = a.z; av[j + 3] = a.w;
            }
        }

        float m = -3.0e38f, d = 0.f;
        float A[16];
#pragma unroll
        for (int j = 0; j < 16; j++) A[j] = 0.f;

        const int* off = csrOff + (size_t)r * (N + 1);
        const unsigned short* sp = csrSrc + (size_t)r * E;
        int kb = off[n], ke = off[n + 1];
        if (kb < ke) {
            int kl = ke - 1;
            int ki = kb + e;
            int s = sp[(ki <= kl) ? ki : kl];
            float c[16];
            {
                const unsigned short* xp = xl + (size_t)s * 256 + cb;
                u16x8 q0 = *(const u16x8*)(xp);
                u16x8 q1 = *(const u16x8*)(xp + 8);
#pragma unroll
                for (int j = 0; j < 8; j++) { c[j] = bf2f(q0[j]); c[8 + j] = bf2f(q1[j]); }
            }
            for (int k = kb; k < ke; k += 4) {
                int kn = k + 4 + e;
                int sn = sp[(kn <= kl) ? kn : kl];
                const unsigned short* np_ = xl + (size_t)sn * 256 + cb;
                u16x8 n0 = *(const u16x8*)(np_);
                u16x8 n1 = *(const u16x8*)(np_ + 8);

                float p = 0.f;
#pragma unroll
                for (int j = 0; j < 16; j++) {
                    float t = c[j] + rv[j];
                    t = (t > 0.f) ? t : 0.2f * t;
                    p = fmaf(t, av[j], p);
                }
                p += __shfl_xor(p, 1, 64);
                p += __shfl_xor(p, 2, 64);
                bool valid = (k + e) < ke;
                if (!valid) p = -3.0e38f;

                if (__any(p > m)) {  // rare after warmup
                    float nm = fmaxf(m, p);
                    float sc = __expf(m - nm);
                    d *= sc;
#pragma unroll
                    for (int j = 0; j < 16; j++) A[j] *= sc;
                    m = nm;
                }
                float wg = valid ? __expf(p - m) : 0.f;
                d += wg;
#pragma unroll
                for (int j = 0; j < 16; j++) A[j] = fmaf(wg, c[j], A[j]);

#pragma unroll
                for (int j = 0; j < 8; j++) { c[j] = bf2f(n0[j]); c[8 + j] = bf2f(n1[j]); }
            }
        }

        float M = fmaxf(m, __shfl_xor(m, 16, 64));
        M = fmaxf(M, __shfl_xor(M, 32, 64));
        float sc = __expf(m - M);
        d *= sc;
        d += __shfl_xor(d, 16, 64);
        d += __shfl_xor(d, 32, 64);
#pragma unroll
        for (int j = 0; j < 16; j++) {
            A[j] *= sc;
            A[j] += __shfl_xor(A[j], 16, 64);
            A[j] += __shfl_xor(A[j], 32, 64);
        }

        float inv = 1.0f / (d + 1e-16f);
        cv.x = fmaf(A[e * 4 + 0], inv, cv.x);
        cv.y = fmaf(A[e * 4 + 1], inv, cv.y);
        cv.z = fmaf(A[e * 4 + 2], inv, cv.z);
        cv.w = fmaf(A[e * 4 + 3], inv, cv.w);
    }

    // relu + split-bf16 pack into MFMA A-fragment layout (KT=8)
    cv.x = fmaxf(cv.x, 0.f);
    cv.y = fmaxf(cv.y, 0.f);
    cv.z = fmaxf(cv.z, 0.f);
    cv.w = fmaxf(cv.w, 0.f);
    float vv[4] = {cv.x, cv.y, cv.z, cv.w};
    bf16x4 hv, lv;
#pragma unroll
    for (int j = 0; j < 4; j++) {
        __bf16 h = (__bf16)vv[j];
        hv[j] = h;
        lv[j] = (__bf16)(vv[j] - (float)h);
    }
    size_t outp = (((size_t)(n >> 4) * 8 + (wc >> 5)) * 64 + ((wc >> 3) & 3) * 16 + (n & 15)) * 8 + (wc & 7);
    *(bf16x4*)(Ah + outp) = hv;
    if (write_lo) *(bf16x4*)(Al + outp) = lv;
}

// ---------------- head ----------------

__global__ __launch_bounds__(256) void head_kernel(const float* __restrict__ hm,
                                                   const float* __restrict__ W2,
                                                   const float* __restrict__ b2,
                                                   float* __restrict__ out, int N) {
    int lane = threadIdx.x & 63;
    int wid = blockIdx.x * 4 + (threadIdx.x >> 6);
    if (wid >= N) return;
    int n = __builtin_amdgcn_readfirstlane(wid);
    float a0 = hm[(size_t)n * 128 + lane];
    float a1 = hm[(size_t)n * 128 + 64 + lane];
    float s0 = a0 * W2[lane * 3 + 0] + a1 * W2[(64 + lane) * 3 + 0];
    float s1 = a0 * W2[lane * 3 + 1] + a1 * W2[(64 + lane) * 3 + 1];
    float s2 = a0 * W2[lane * 3 + 2] + a1 * W2[(64 + lane) * 3 + 2];
#pragma unroll
    for (int sft = 1; sft < 64; sft <<= 1) {
        s0 += __shfl_xor(s0, sft, 64);
        s1 += __shfl_xor(s1, sft, 64);
        s2 += __shfl_xor(s2, sft, 64);
    }
    if (lane == 0) {
        out[(size_t)n * 3 + 0] = s0 + b2[0];
        out[(size_t)n * 3 + 1] = s1 + b2[1];
        out[(size_t)n * 3 + 2] = s2 + b2[2];
    }
}

// ---------------- launch ----------------

extern "C" void kernel_launch(void* const* d_in, const int* in_sizes, int n_in,
                              void* d_out, int out_size, void* d_ws, size_t ws_size,
                              hipStream_t stream) {
    const float* x    = (const float*)d_in[0];
    const int* date   = (const int*)d_in[1];
    const int* ei     = (const int*)d_in[2];
    const float* pW   = (const float*)d_in[3];
    const float* pb   = (const float*)d_in[4];
    const float* Wl0  = (const float*)d_in[5];
    const float* Wr0  = (const float*)d_in[6];
    const float* att0 = (const float*)d_in[7];
    const float* b0   = (const float*)d_in[8];
    const float* Wl1  = (const float*)d_in[9];
    const float* Wr1  = (const float*)d_in[10];
    const float* att1 = (const float*)d_in[11];
    const float* b1   = (const float*)d_in[12];
    // d_in[13..15] = aggW/aggb/agga — rel_agg is identity (h_rel broadcast), skipped
    const float* outW1 = (const float*)d_in[16];
    const float* outb1 = (const float*)d_in[17];
    const float* outW2 = (const float*)d_in[18];
    const float* outb2 = (const float*)d_in[19];
    float* out = (float*)d_out;

    int N = in_sizes[0] / 64;
    int E = in_sizes[2] / 10;
    int Mp = ((N + 127) / 128) * 128;
    int MT = Mp / 128;
    int MT8 = (MT + 7) / 8;  // bx octets
    int NC = (N + 1023) / 1024;

    char* ws = (char*)d_ws;
    size_t o = 0;
    auto alloc = [&](size_t bytes) -> char* {
        char* p = ws + o;
        o += (bytes + 255) & ~(size_t)255;
        return p;
    };
    int* cur               = (int*)alloc((size_t)5 * N * 4);
    int* csrOff            = (int*)alloc((size_t)5 * (N + 1) * 4);
    unsigned short* csrSrc = (unsigned short*)alloc((size_t)5 * E * 2);
    int* csums             = (int*)alloc((size_t)5 * NC * 4);
    unsigned short* xb16   = (unsigned short*)alloc((size_t)N * 64 * 2);
    float* h0              = (float*)alloc((size_t)N * 112 * 4);
    unsigned short* xl5    = (unsigned short*)alloc((size_t)5 * N * 256 * 2);
    unsigned short* xr5    = (unsigned short*)alloc((size_t)5 * N * 256 * 2);
    __bf16* Aph            = (__bf16*)alloc((size_t)Mp * 256 * 2);
    __bf16* Apl            = (__bf16*)alloc((size_t)Mp * 256 * 2);
    __bf16* Wph            = (__bf16*)alloc((size_t)1015808 * 2);
    __bf16* Wpl            = (__bf16*)alloc((size_t)1015808 * 2);
    float* hmid            = (float*)xl5;  // xl5 dead after layer-1 gat
    (void)ws_size;

    const size_t S0 = 32768, S1 = 65536;
    const size_t oWl0 = 0, oWr0 = 163840, oWl1 = 327680, oWr1 = 655360, oW1 = 983040;
    size_t xstride = (size_t)N * 256 * 2;

    int totE = 5 * E;
    const size_t GEMM_LDS = 32768;

    // CSR by dst, per relation
    hipMemsetAsync(cur, 0, (size_t)5 * N * 4, stream);
    count_kernel<<<(totE + 255) / 256, 256, 0, stream>>>(ei, cur, N, E);
    scanA_kernel<<<dim3(NC, 5), 256, 0, stream>>>(cur, csrOff, csums, N, NC);
    scanB_kernel<<<1, 64, 0, stream>>>(csums, csrOff, N, NC);
    scanC_kernel<<<dim3(NC, 5), 256, 0, stream>>>(csrOff, csums, cur, N, NC);
    scatter_kernel<<<(totE + 255) / 256, 256, 0, stream>>>(ei, cur, csrSrc, N, E);

    // x -> bf16 copy + pearl PE + time PE + concat
    xcvt_kernel<<<(N * 64 / 4 + 255) / 256, 256, 0, stream>>>(x, xb16, N * 64);
    pearl_h0_kernel<<<(N + 3) / 4, 256, 0, stream>>>(x, xb16, date, csrOff, csrSrc, pW, pb, h0, N, E);

    // pack all weights (lo plane only for head W1)
    pack_w_kernel<<<dim3(32, 21, 1), 256, 0, stream>>>(Wl0, Wr0, Wl1, Wr1, outW1, Wph, Wpl);

    // ----- layer 0 (K=112 -> Kp=128, KT=4): npL=npR=1, kstep=2 -----
    pack_a_kernel<<<(Mp * 16 + 255) / 256, 256, 0, stream>>>(h0, Aph, Apl, N, 112, Mp, 4, 0);
    gemm_mfma<<<MT8 * 8 * 20, 256, GEMM_LDS, stream>>>(
        Aph, Apl, Wph + oWl0, Wpl + oWl0, Wph + oWr0, Wpl + oWr0, S0,
        xl5, xr5, xstride, N, 256, 4, nullptr, 0, 1, 1, 1, 2, MT, 20, 2);
    gat5_kernel<<<(N + 3) / 4, 256, 0, stream>>>(xl5, xr5, att0, csrOff, csrSrc,
                                                 Aph, Apl, b0, N, E, 0);

    // ----- layer 1 (K=256, KT=8): npL=npR=1, kstep=2 -----
    gemm_mfma<<<MT8 * 8 * 20, 256, GEMM_LDS, stream>>>(
        Aph, Apl, Wph + oWl1, Wpl + oWl1, Wph + oWr1, Wpl + oWr1, S1,
        xl5, xr5, xstride, N, 256, 8, nullptr, 0, 1, 1, 1, 2, MT, 20, 2);
    gat5_kernel<<<(N + 3) / 4, 256, 0, stream>>>(xl5, xr5, att1, csrOff, csrSrc,
                                                 Aph, Apl, b1, N, E, 1);

    // ----- MLP head: hmid = relu(packedA @ outW1 + outb1), 3-pass, kstep=1 -----
    gemm_mfma<<<MT8 * 8, 256, GEMM_LDS, stream>>>(
        Aph, Apl, Wph + oW1, Wpl + oW1, Wph + oW1, Wpl + oW1, 0,
        hmid, hmid, 0, N, 128, 8, outb1, 1, 3, 3, 0, 1, MT, 1, 1);
    head_kernel<<<(N + 3) / 4, 256, 0, stream>>>(hmid, outW2, outb2, out, N);
}